// Round 8
// baseline (138.622 us; speedup 1.0000x reference)
//
#include <hip/hip_runtime.h>
#include <math.h>

// Problem constants (fixed by the reference)
#define N_NODES 50000
#define N_EDGES 800000
#define FN_DIM 16
#define HD 64
#define T_CAP 8192     // cap on |need1| (measured ~355) = layer-0 targets
#define T2_CAP 512     // cap on |need2| (measured ~17)  = layer-1 targets
#define MAXDEG 128     // cap on in-degree (Poisson(16))
#define LGRID 512      // layer kernel grid
#define L1BLK 64       // blocks that continue into layer 1

struct KP {
  const float *x; const int *ei;
  const float *Wn,*bn,*gn,*betan;
  const float *Wc1,*bc1,*Wc2,*bc2;
  const float *Wg,*att_s,*att_d,*bg;
  const float *Wq1,*bq1,*gq,*betaq,*Wq2,*bq2;
  const float *Wv1,*bv1,*gv,*betav,*Wv2,*bv2;
  float *out;
  float *hB,*hA;
  int *need1,*need2,*deg1,*deg2,*deg3,*cnt,*idx1,*idx2,*list1,*list2,*eb1,*eb2,*eb3;
};

// ---------- wave-64 helpers ----------
__device__ __forceinline__ float wsum64(float v) {
    #pragma unroll
    for (int o = 1; o < 64; o <<= 1) v += __shfl_xor(v, o);
    return v;
}
__device__ __forceinline__ float wmax64(float v) {
    #pragma unroll
    for (int o = 1; o < 64; o <<= 1) v = fmaxf(v, __shfl_xor(v, o));
    return v;
}
__device__ __forceinline__ float lrelu02(float v) { return v > 0.f ? v : 0.2f * v; }

// ---------- zero the flag/counter zone ----------
__global__ void k_zero(int4* __restrict__ p, int n4) {
    int i = blockIdx.x * blockDim.x + threadIdx.x;
    if (i < n4) p[i] = make_int4(0, 0, 0, 0);
}

// ---------- scan A: edges into node 0 -> eb3, seed/mark need2 & need1 (+lists/idx) ----------
__global__ void k_scanA(const int* __restrict__ ei,
                        int* need1, int* need2, int* list1, int* list2,
                        int* idx1, int* idx2, int* cnt, int* eb3, int* deg3) {
    int e = blockIdx.x * blockDim.x + threadIdx.x;
    if (e == 0) {   // seed node 0 (same dedup protocol as edge hits)
        if (atomicExch(&need2[0], 1) == 0) { int p = atomicAdd(&cnt[1], 1); if (p < T2_CAP) { list2[p] = 0; idx2[0] = p; } }
        if (atomicExch(&need1[0], 1) == 0) { int p = atomicAdd(&cnt[0], 1); if (p < T_CAP)  { list1[p] = 0; idx1[0] = p; } }
    }
    if (e >= N_EDGES) return;
    if (ei[N_EDGES + e] == 0) {
        int s = ei[e];
        int p = atomicAdd(deg3, 1); if (p < MAXDEG) eb3[p] = s;
        if (atomicExch(&need2[s], 1) == 0) { int q = atomicAdd(&cnt[1], 1); if (q < T2_CAP) { list2[q] = s; idx2[s] = q; } }
        if (atomicExch(&need1[s], 1) == 0) { int q = atomicAdd(&cnt[0], 1); if (q < T_CAP)  { list1[q] = s; idx1[s] = q; } }
    }
}

// ---------- scan B: edges into need2 -> eb2 buckets; mark need1 sources ----------
__global__ void k_scanB(const int* __restrict__ ei, const int* __restrict__ need2,
                        const int* __restrict__ idx2,
                        int* need1, int* list1, int* idx1, int* cnt,
                        int* eb2, int* deg2) {
    int e = blockIdx.x * blockDim.x + threadIdx.x;
    if (e >= N_EDGES) return;
    int d = ei[N_EDGES + e];
    if (need2[d]) {
        int s = ei[e];
        unsigned t = (unsigned)idx2[d];
        if (t < T2_CAP) { int p = atomicAdd(&deg2[t], 1); if (p < MAXDEG) eb2[t * MAXDEG + p] = s; }
        if (atomicExch(&need1[s], 1) == 0) { int q = atomicAdd(&cnt[0], 1); if (q < T_CAP) { list1[q] = s; idx1[s] = q; } }
    }
}

// ---------- scan C: edges into need1 -> eb1 buckets ----------
__global__ void k_scanC(const int* __restrict__ ei, const int* __restrict__ need1,
                        const int* __restrict__ idx1, int* eb1, int* deg1) {
    int e = blockIdx.x * blockDim.x + threadIdx.x;
    if (e >= N_EDGES) return;
    int d = ei[N_EDGES + e];
    if (need1[d]) {
        unsigned t = (unsigned)idx1[d];
        if (t < T_CAP) { int p = atomicAdd(&deg1[t], 1); if (p < MAXDEG) eb1[t * MAXDEG + p] = ei[e]; }
    }
}

// ---------- node feature: layer 0 encodes from x, later layers load h ----------
__device__ __forceinline__ float node_h(int lm, int i, int lane, const KP& p,
                                        const float* __restrict__ hin) {
    if (lm == 0) {
        float acc = p.bn[lane];
        #pragma unroll
        for (int k = 0; k < FN_DIM; k++) acc += p.x[i * FN_DIM + k] * p.Wn[k * HD + lane];
        float v = fmaxf(acc, 0.f);
        float mu = wsum64(v) * (1.f / 64.f);
        float d = v - mu;
        float var = wsum64(d * d) * (1.f / 64.f);
        return d * rsqrtf(var + 1e-5f) * p.gn[lane] + p.betan[lane];
    } else {
        return hin[(size_t)i * HD + lane];
    }
}

// ---------- heads (wave 0 only), writes out[0..32] ----------
__device__ __forceinline__ void heads_eval(float hv, int lane, const KP& p) {
    float acc = p.bq1[lane];
    #pragma unroll 8
    for (int k = 0; k < 64; k++) acc += __shfl(hv, k) * p.Wq1[k * 64 + lane];
    float r = fmaxf(acc, 0.f);
    float mu = wsum64(r) * (1.f / 64.f);
    float d = r - mu;
    float var = wsum64(d * d) * (1.f / 64.f);
    float tq = d * rsqrtf(var + 1e-5f) * p.gq[lane] + p.betaq[lane];
    float accv = p.bv1[lane];
    #pragma unroll 8
    for (int k = 0; k < 64; k++) accv += __shfl(hv, k) * p.Wv1[k * 64 + lane];
    float rv = fmaxf(accv, 0.f);
    float muv = wsum64(rv) * (1.f / 64.f);
    float dv = rv - muv;
    float varv = wsum64(dv * dv) * (1.f / 64.f);
    float tv = dv * rsqrtf(varv + 1e-5f) * p.gv[lane] + p.betav[lane];
    int s = lane & 31;
    float q = p.bq2[s];
    #pragma unroll 8
    for (int k = 0; k < 64; k++) q += __shfl(tq, k) * p.Wq2[k * 32 + s];
    if (lane < 32) p.out[lane] = q;
    float vsum = wsum64(tv * p.Wv2[lane]);
    if (lane == 0) p.out[32] = vsum + p.bv2[0];
}

// ---------- all 3 layers in one kernel; r3's proven per-target body ----------
// Barriers are arrive-then-maybe-exit (deadlock-safe without cooperative launch:
// arrival never waits; spinners (<=64) < #CUs so remaining blocks always progress).
__global__ __launch_bounds__(256) void k_layers(KP p) {
    __shared__ float ht[64], ut[64], xgt[64];
    __shared__ float scr[4][4][64];     // per-wave 4-edge vector scratch
    __shared__ float xgc[MAXDEG][64];   // per-edge xg cache
    __shared__ float ec[MAXDEG];        // per-edge attention logit
    __shared__ float redA[4][64], redB[4][64];
    __shared__ float sws[4];
    __shared__ float sA[2];             // a_s[t], a_d[t]
    __shared__ float sEm;

    const int tid = threadIdx.x;
    const int lane = tid & 63;
    const int wv = tid >> 6;
    const int bid = blockIdx.x;

    for (int lm = 0; lm < 3; lm++) {
        // per-phase selects
        int ntgt, stride;
        const int *tl, *ebp, *dgp;
        const float *hin;
        float *hout;
        const float *Wc1l = p.Wc1 + lm * 2 * HD * HD, *bc1l = p.bc1 + lm * HD;
        const float *Wc2l = p.Wc2 + lm * HD * HD,     *bc2l = p.bc2 + lm * HD;
        const float *Wgl  = p.Wg  + lm * HD * HD,     *bgl  = p.bg  + lm * HD;
        const float *attsl = p.att_s + lm * HD, *attdl = p.att_d + lm * HD;
        if (lm == 0)      { ntgt = min(p.cnt[0], T_CAP);  tl = p.list1; ebp = p.eb1; dgp = p.deg1; hin = p.hA; hout = p.hB; stride = gridDim.x; }
        else if (lm == 1) { ntgt = min(p.cnt[1], T2_CAP); tl = p.list2; ebp = p.eb2; dgp = p.deg2; hin = p.hB; hout = p.hA; stride = L1BLK; }
        else              { ntgt = 1;                     tl = nullptr; ebp = p.eb3; dgp = p.deg3; hin = p.hA; hout = p.out; stride = 1; }

        for (int w = bid; w < ntgt; w += stride) {
            int t = (lm == 2) ? 0 : tl[w];
            const int* row = ebp + (size_t)((lm == 2) ? 0 : w) * MAXDEG;
            if (wv == 0) {
                float h = node_h(lm, t, lane, p, hin);
                ht[lane] = h;
                float u = bc1l[lane], xg = 0.f;
                #pragma unroll 4
                for (int k = 0; k < 64; k++) {
                    float b = ht[k];
                    u  += b * Wc1l[k * 64 + lane];
                    xg += b * Wgl[k * 64 + lane];
                }
                ut[lane] = u; xgt[lane] = xg;
                float a_st = wsum64(xg * attsl[lane]);
                float a_dt = wsum64(xg * attdl[lane]);
                if (lane == 0) { sA[0] = a_st; sA[1] = a_dt; }
            }
            __syncthreads();
            int dg = dgp[(lm == 2) ? 0 : w]; if (dg > MAXDEG) dg = MAXDEG;
            float a_dt = sA[1];
            float aggw = -INFINITY;

            for (int base = wv * 4; base < dg; base += 16) {
                int ne = dg - base; if (ne > 4) ne = 4;
                #pragma unroll
                for (int e = 0; e < 4; e++) {
                    if (e < ne) {
                        int s = row[base + e];
                        scr[wv][e][lane] = node_h(lm, s, lane, p, hin);
                    }
                }
                float v[4] = {0.f, 0.f, 0.f, 0.f};
                float g[4] = {0.f, 0.f, 0.f, 0.f};
                #pragma unroll 4
                for (int k = 0; k < 64; k++) {
                    float wc = Wc1l[(64 + k) * 64 + lane];
                    float wg = Wgl[k * 64 + lane];
                    #pragma unroll
                    for (int e = 0; e < 4; e++) {
                        float b = scr[wv][e][k];
                        v[e] += b * wc;
                        g[e] += b * wg;
                    }
                }
                float ut_l = ut[lane];
                #pragma unroll
                for (int e = 0; e < 4; e++) scr[wv][e][lane] = fmaxf(ut_l + v[e], 0.f);
                float m[4];
                #pragma unroll
                for (int e = 0; e < 4; e++) m[e] = bc2l[lane];
                #pragma unroll 4
                for (int k = 0; k < 64; k++) {
                    float wc2v = Wc2l[k * 64 + lane];
                    #pragma unroll
                    for (int e = 0; e < 4; e++) m[e] += scr[wv][e][k] * wc2v;
                }
                #pragma unroll
                for (int e = 0; e < 4; e++) {
                    if (e < ne) {
                        aggw = fmaxf(aggw, m[e]);
                        int j = base + e;
                        xgc[j][lane] = g[e];
                        float a_ss = wsum64(g[e] * attsl[lane]);
                        if (lane == 0) ec[j] = lrelu02(a_ss + a_dt);
                    }
                }
            }
            redA[wv][lane] = aggw;
            __syncthreads();

            if (wv == 0) {
                float es = lrelu02(sA[0] + sA[1]);
                float mm = es;
                for (int j = lane; j < dg; j += 64) mm = fmaxf(mm, ec[j]);
                mm = wmax64(mm);
                if (lane == 0) sEm = mm;
            }
            __syncthreads();
            float em = sEm;
            float attv = 0.f, wsv = 0.f;
            for (int j = wv; j < dg; j += 4) {
                float wj = expf(ec[j] - em);
                attv += wj * xgc[j][lane];
                wsv += wj;
            }
            redB[wv][lane] = attv;
            if (lane == 0) sws[wv] = wsv;
            __syncthreads();

            if (wv == 0) {
                float agg = fmaxf(fmaxf(redA[0][lane], redA[1][lane]),
                                  fmaxf(redA[2][lane], redA[3][lane]));
                if (dg == 0) agg = 0.f;   // PyG scatter-max: empty segment -> 0
                float es = lrelu02(sA[0] + sA[1]);
                float wself = expf(es - em);
                float att = redB[0][lane] + redB[1][lane] + redB[2][lane] + redB[3][lane]
                          + wself * xgt[lane];
                float wsum = sws[0] + sws[1] + sws[2] + sws[3] + wself;
                float hv = fmaxf(ht[lane] + agg + att / wsum + bgl[lane], 0.f);
                if (lm == 2) heads_eval(hv, lane, p);
                else hout[(size_t)t * HD + lane] = hv;
            }
            __syncthreads();
        }

        // ---- inter-phase barrier (arrive; exit if not needed; else spin)
        if (lm == 0) {
            __builtin_amdgcn_fence(__ATOMIC_RELEASE, "agent");
            __syncthreads();
            if (tid == 0) atomicAdd(&p.cnt[2], 1);
            if (bid >= L1BLK) return;
            if (tid == 0) {
                while (__hip_atomic_load(&p.cnt[2], __ATOMIC_RELAXED, __HIP_MEMORY_SCOPE_AGENT) < (int)gridDim.x)
                    __builtin_amdgcn_s_sleep(8);
            }
            __syncthreads();
            __builtin_amdgcn_fence(__ATOMIC_ACQUIRE, "agent");
        } else if (lm == 1) {
            __builtin_amdgcn_fence(__ATOMIC_RELEASE, "agent");
            __syncthreads();
            if (tid == 0) atomicAdd(&p.cnt[3], 1);
            if (bid != 0) return;
            if (tid == 0) {
                while (__hip_atomic_load(&p.cnt[3], __ATOMIC_RELAXED, __HIP_MEMORY_SCOPE_AGENT) < L1BLK)
                    __builtin_amdgcn_s_sleep(8);
            }
            __syncthreads();
            __builtin_amdgcn_fence(__ATOMIC_ACQUIRE, "agent");
        }
    }
}

extern "C" void kernel_launch(void* const* d_in, const int* in_sizes, int n_in,
                              void* d_out, int out_size, void* d_ws, size_t ws_size,
                              hipStream_t stream) {
    KP p;
    p.x      = (const float*)d_in[0];
    p.ei     = (const int*)d_in[1];
    // d_in[2] edge_attr and d_in[7..10] (edge encoder) are dead code in the reference
    p.Wn     = (const float*)d_in[3];
    p.bn     = (const float*)d_in[4];
    p.gn     = (const float*)d_in[5];
    p.betan  = (const float*)d_in[6];
    p.Wc1    = (const float*)d_in[11];
    p.bc1    = (const float*)d_in[12];
    p.Wc2    = (const float*)d_in[13];
    p.bc2    = (const float*)d_in[14];
    p.Wg     = (const float*)d_in[15];
    p.att_s  = (const float*)d_in[16];
    p.att_d  = (const float*)d_in[17];
    p.bg     = (const float*)d_in[18];
    p.Wq1    = (const float*)d_in[19];
    p.bq1    = (const float*)d_in[20];
    p.gq     = (const float*)d_in[21];
    p.betaq  = (const float*)d_in[22];
    p.Wq2    = (const float*)d_in[23];
    p.bq2    = (const float*)d_in[24];
    p.Wv1    = (const float*)d_in[25];
    p.bv1    = (const float*)d_in[26];
    p.gv     = (const float*)d_in[27];
    p.betav  = (const float*)d_in[28];
    p.Wv2    = (const float*)d_in[29];
    p.bv2    = (const float*)d_in[30];
    p.out    = (float*)d_out;

    // ---- workspace layout (identical ordering to r3/r7)
    p.hB    = (float*)d_ws;                         // N*HD
    p.hA    = p.hB + (size_t)N_NODES * HD;          // N*HD
    p.need1 = (int*)(p.hA + (size_t)N_NODES * HD);  // zero-zone start (16B aligned)
    p.need2 = p.need1 + N_NODES;
    p.deg1  = p.need2 + N_NODES;                    // T_CAP
    p.deg2  = p.deg1 + T_CAP;                       // T2_CAP
    p.deg3  = p.deg2 + T2_CAP;                      // 4
    p.cnt   = p.deg3 + 4;                           // 8: cnt0,cnt1,done0,done1 (zero-zone end)
    p.idx1  = p.cnt + 8;                            // N
    p.idx2  = p.idx1 + N_NODES;                     // N
    p.list1 = p.idx2 + N_NODES;                     // T_CAP
    p.list2 = p.list1 + T_CAP;                      // T2_CAP
    p.eb1   = p.list2 + T2_CAP;                     // T_CAP*MAXDEG
    p.eb2   = p.eb1 + (size_t)T_CAP * MAXDEG;       // T2_CAP*MAXDEG
    p.eb3   = p.eb2 + (size_t)T2_CAP * MAXDEG;      // MAXDEG

    const int zero_ints = 2 * N_NODES + T_CAP + T2_CAP + 12;   // 108716, /4 exact
    const int n4 = zero_ints / 4;                   // 27179 int4
    const int EB = (N_EDGES + 255) / 256;           // 3125 blocks

    k_zero<<<(n4 + 255) / 256, 256, 0, stream>>>((int4*)p.need1, n4);
    k_scanA<<<EB, 256, 0, stream>>>(p.ei, p.need1, p.need2, p.list1, p.list2,
                                    p.idx1, p.idx2, p.cnt, p.eb3, p.deg3);
    k_scanB<<<EB, 256, 0, stream>>>(p.ei, p.need2, p.idx2,
                                    p.need1, p.list1, p.idx1, p.cnt, p.eb2, p.deg2);
    k_scanC<<<EB, 256, 0, stream>>>(p.ei, p.need1, p.idx1, p.eb1, p.deg1);
    k_layers<<<LGRID, 256, 0, stream>>>(p);
}

// Round 9
// 101.379 us; speedup vs baseline: 1.3674x; 1.3674x over previous
//
#include <hip/hip_runtime.h>
#include <math.h>

// Problem constants (fixed by the reference)
#define N_NODES 50000
#define N_EDGES 800000
#define FN_DIM 16
#define HD 64
#define T_CAP 8192     // cap on |need1| (measured ~355) = layer-0 targets
#define T2_CAP 512     // cap on |need2| (measured ~17)  = layer-1 targets
#define MAXDEG 128     // cap on in-degree (Poisson(16))
#define L12BLK 32      // blocks for merged layer1+2 kernel

struct KP {
  const float *x; const int *ei;
  const float *Wn,*bn,*gn,*betan;
  const float *Wc1,*bc1,*Wc2,*bc2;
  const float *Wg,*att_s,*att_d,*bg;
  const float *Wq1,*bq1,*gq,*betaq,*Wq2,*bq2;
  const float *Wv1,*bv1,*gv,*betav,*Wv2,*bv2;
  float *out;
  float *hB,*hA;
  int *need1,*need2,*deg1,*deg2,*deg3,*cnt,*idx1,*idx2,*list1,*list2,*eb1,*eb2,*eb3;
};

// ---------- wave-64 helpers ----------
__device__ __forceinline__ float wsum64(float v) {
    #pragma unroll
    for (int o = 1; o < 64; o <<= 1) v += __shfl_xor(v, o);
    return v;
}
__device__ __forceinline__ float wmax64(float v) {
    #pragma unroll
    for (int o = 1; o < 64; o <<= 1) v = fmaxf(v, __shfl_xor(v, o));
    return v;
}
__device__ __forceinline__ float lrelu02(float v) { return v > 0.f ? v : 0.2f * v; }

// ---------- zero the flag/counter zone ----------
__global__ void k_zero(int4* __restrict__ p, int n4) {
    int i = blockIdx.x * blockDim.x + threadIdx.x;
    if (i < n4) p[i] = make_int4(0, 0, 0, 0);
}

// ---------- scan A: edges into node 0 -> eb3, seed/mark need2 & need1 (+lists/idx) ----------
__global__ void k_scanA(const int* __restrict__ ei,
                        int* need1, int* need2, int* list1, int* list2,
                        int* idx1, int* idx2, int* cnt, int* eb3, int* deg3) {
    int e = blockIdx.x * blockDim.x + threadIdx.x;
    if (e == 0) {   // seed node 0 (same dedup protocol as edge hits)
        if (atomicExch(&need2[0], 1) == 0) { int p = atomicAdd(&cnt[1], 1); if (p < T2_CAP) { list2[p] = 0; idx2[0] = p; } }
        if (atomicExch(&need1[0], 1) == 0) { int p = atomicAdd(&cnt[0], 1); if (p < T_CAP)  { list1[p] = 0; idx1[0] = p; } }
    }
    if (e >= N_EDGES) return;
    if (ei[N_EDGES + e] == 0) {
        int s = ei[e];
        int p = atomicAdd(deg3, 1); if (p < MAXDEG) eb3[p] = s;
        if (atomicExch(&need2[s], 1) == 0) { int q = atomicAdd(&cnt[1], 1); if (q < T2_CAP) { list2[q] = s; idx2[s] = q; } }
        if (atomicExch(&need1[s], 1) == 0) { int q = atomicAdd(&cnt[0], 1); if (q < T_CAP)  { list1[q] = s; idx1[s] = q; } }
    }
}

// ---------- scan B: edges into need2 -> eb2 buckets; mark need1 sources ----------
__global__ void k_scanB(const int* __restrict__ ei, const int* __restrict__ need2,
                        const int* __restrict__ idx2,
                        int* need1, int* list1, int* idx1, int* cnt,
                        int* eb2, int* deg2) {
    int e = blockIdx.x * blockDim.x + threadIdx.x;
    if (e >= N_EDGES) return;
    int d = ei[N_EDGES + e];
    if (need2[d]) {
        int s = ei[e];
        unsigned t = (unsigned)idx2[d];
        if (t < T2_CAP) { int p = atomicAdd(&deg2[t], 1); if (p < MAXDEG) eb2[t * MAXDEG + p] = s; }
        if (atomicExch(&need1[s], 1) == 0) { int q = atomicAdd(&cnt[0], 1); if (q < T_CAP) { list1[q] = s; idx1[s] = q; } }
    }
}

// ---------- scan C: edges into need1 -> eb1 buckets ----------
__global__ void k_scanC(const int* __restrict__ ei, const int* __restrict__ need1,
                        const int* __restrict__ idx1, int* eb1, int* deg1) {
    int e = blockIdx.x * blockDim.x + threadIdx.x;
    if (e >= N_EDGES) return;
    int d = ei[N_EDGES + e];
    if (need1[d]) {
        unsigned t = (unsigned)idx1[d];
        if (t < T_CAP) { int p = atomicAdd(&deg1[t], 1); if (p < MAXDEG) eb1[t * MAXDEG + p] = ei[e]; }
    }
}

// ---------- shared-memory block for the layer body ----------
struct SMem {
    float ht[64], ut[64], xgt[64];
    float scr[4][4][64];     // per-wave 4-edge vector scratch
    float xgc[MAXDEG][64];   // per-edge xg cache
    float ec[MAXDEG];        // per-edge attention logit
    float redA[4][64], redB[4][64];
    float sws[4];
    float sA[2];             // a_s[t], a_d[t]
    float sEm;
};

// ---------- node feature: layer 0 encodes from x, later layers load h ----------
template<int LM>
__device__ __forceinline__ float node_h(int i, int lane, const KP& p,
                                        const float* __restrict__ hin) {
    if (LM == 0) {
        float acc = p.bn[lane];
        #pragma unroll
        for (int k = 0; k < FN_DIM; k++) acc += p.x[i * FN_DIM + k] * p.Wn[k * HD + lane];
        float v = fmaxf(acc, 0.f);
        float mu = wsum64(v) * (1.f / 64.f);
        float d = v - mu;
        float var = wsum64(d * d) * (1.f / 64.f);
        return d * rsqrtf(var + 1e-5f) * p.gn[lane] + p.betan[lane];
    } else {
        return hin[(size_t)i * HD + lane];
    }
}

// ---------- heads (wave 0 only), writes out[0..32] ----------
__device__ __forceinline__ void heads_eval(float hv, int lane, const KP& p) {
    float acc = p.bq1[lane];
    #pragma unroll 8
    for (int k = 0; k < 64; k++) acc += __shfl(hv, k) * p.Wq1[k * 64 + lane];
    float r = fmaxf(acc, 0.f);
    float mu = wsum64(r) * (1.f / 64.f);
    float d = r - mu;
    float var = wsum64(d * d) * (1.f / 64.f);
    float tq = d * rsqrtf(var + 1e-5f) * p.gq[lane] + p.betaq[lane];
    float accv = p.bv1[lane];
    #pragma unroll 8
    for (int k = 0; k < 64; k++) accv += __shfl(hv, k) * p.Wv1[k * 64 + lane];
    float rv = fmaxf(accv, 0.f);
    float muv = wsum64(rv) * (1.f / 64.f);
    float dv = rv - muv;
    float varv = wsum64(dv * dv) * (1.f / 64.f);
    float tv = dv * rsqrtf(varv + 1e-5f) * p.gv[lane] + p.betav[lane];
    int s = lane & 31;
    float q = p.bq2[s];
    #pragma unroll 8
    for (int k = 0; k < 64; k++) q += __shfl(tq, k) * p.Wq2[k * 32 + s];
    if (lane < 32) p.out[lane] = q;
    float vsum = wsum64(tv * p.Wv2[lane]);
    if (lane == 0) p.out[32] = vsum + p.bv2[0];
}

// ---------- the r3/r7-proven per-target layer body (template LM, inlined) ----------
template<int LM>
__device__ __forceinline__ void layer_phase(const KP& p, SMem& sm,
                                            const float* __restrict__ hin,
                                            float* __restrict__ hout) {
    const int lane = threadIdx.x & 63;
    const int wv = threadIdx.x >> 6;
    const float* Wc1l = p.Wc1 + LM * 2 * HD * HD;
    const float* bc1l = p.bc1 + LM * HD;
    const float* Wc2l = p.Wc2 + LM * HD * HD;
    const float* bc2l = p.bc2 + LM * HD;
    const float* Wgl  = p.Wg  + LM * HD * HD;
    const float* bgl  = p.bg  + LM * HD;
    const float* attsl = p.att_s + LM * HD;
    const float* attdl = p.att_d + LM * HD;
    const int* tl  = (LM == 0) ? p.list1 : p.list2;
    const int* ebp = (LM == 0) ? p.eb1 : (LM == 1) ? p.eb2 : p.eb3;
    const int* dgp = (LM == 0) ? p.deg1 : (LM == 1) ? p.deg2 : p.deg3;
    int ntgt = (LM == 0) ? min(p.cnt[0], T_CAP) : (LM == 1) ? min(p.cnt[1], T2_CAP) : 1;

    for (int w = blockIdx.x; w < ntgt; w += gridDim.x) {
        int t = (LM == 2) ? 0 : tl[w];
        const int* row = ebp + (LM == 2 ? 0 : w) * MAXDEG;
        if (wv == 0) {
            float h = node_h<LM>(t, lane, p, hin);
            sm.ht[lane] = h;
            float u = bc1l[lane], xg = 0.f;
            #pragma unroll 4
            for (int k = 0; k < 64; k++) {
                float b = sm.ht[k];
                u  += b * Wc1l[k * 64 + lane];
                xg += b * Wgl[k * 64 + lane];
            }
            sm.ut[lane] = u; sm.xgt[lane] = xg;
            float a_st = wsum64(xg * attsl[lane]);
            float a_dt = wsum64(xg * attdl[lane]);
            if (lane == 0) { sm.sA[0] = a_st; sm.sA[1] = a_dt; }
        }
        __syncthreads();
        int dg = dgp[(LM == 2) ? 0 : w]; if (dg > MAXDEG) dg = MAXDEG;
        float a_dt = sm.sA[1];
        float aggw = -INFINITY;

        for (int base = wv * 4; base < dg; base += 16) {
            int ne = dg - base; if (ne > 4) ne = 4;
            #pragma unroll
            for (int e = 0; e < 4; e++) {
                if (e < ne) {
                    int s = row[base + e];
                    sm.scr[wv][e][lane] = node_h<LM>(s, lane, p, hin);
                }
            }
            float v[4] = {0.f, 0.f, 0.f, 0.f};
            float g[4] = {0.f, 0.f, 0.f, 0.f};
            #pragma unroll 4
            for (int k = 0; k < 64; k++) {
                float wc = Wc1l[(64 + k) * 64 + lane];
                float wg = Wgl[k * 64 + lane];
                #pragma unroll
                for (int e = 0; e < 4; e++) {
                    float b = sm.scr[wv][e][k];
                    v[e] += b * wc;
                    g[e] += b * wg;
                }
            }
            float ut_l = sm.ut[lane];
            #pragma unroll
            for (int e = 0; e < 4; e++) sm.scr[wv][e][lane] = fmaxf(ut_l + v[e], 0.f);
            float m[4];
            #pragma unroll
            for (int e = 0; e < 4; e++) m[e] = bc2l[lane];
            #pragma unroll 4
            for (int k = 0; k < 64; k++) {
                float wc2v = Wc2l[k * 64 + lane];
                #pragma unroll
                for (int e = 0; e < 4; e++) m[e] += sm.scr[wv][e][k] * wc2v;
            }
            #pragma unroll
            for (int e = 0; e < 4; e++) {
                if (e < ne) {
                    aggw = fmaxf(aggw, m[e]);
                    int j = base + e;
                    sm.xgc[j][lane] = g[e];
                    float a_ss = wsum64(g[e] * attsl[lane]);
                    if (lane == 0) sm.ec[j] = lrelu02(a_ss + a_dt);
                }
            }
        }
        sm.redA[wv][lane] = aggw;
        __syncthreads();

        if (wv == 0) {
            float es = lrelu02(sm.sA[0] + sm.sA[1]);
            float mm = es;
            for (int j = lane; j < dg; j += 64) mm = fmaxf(mm, sm.ec[j]);
            mm = wmax64(mm);
            if (lane == 0) sm.sEm = mm;
        }
        __syncthreads();
        float em = sm.sEm;
        float attv = 0.f, wsv = 0.f;
        for (int j = wv; j < dg; j += 4) {
            float wj = expf(sm.ec[j] - em);
            attv += wj * sm.xgc[j][lane];
            wsv += wj;
        }
        sm.redB[wv][lane] = attv;
        if (lane == 0) sm.sws[wv] = wsv;
        __syncthreads();

        if (wv == 0) {
            float agg = fmaxf(fmaxf(sm.redA[0][lane], sm.redA[1][lane]),
                              fmaxf(sm.redA[2][lane], sm.redA[3][lane]));
            if (dg == 0) agg = 0.f;   // PyG scatter-max: empty segment -> 0
            float es = lrelu02(sm.sA[0] + sm.sA[1]);
            float wself = expf(es - em);
            float att = sm.redB[0][lane] + sm.redB[1][lane] + sm.redB[2][lane] + sm.redB[3][lane]
                      + wself * sm.xgt[lane];
            float wsum = sm.sws[0] + sm.sws[1] + sm.sws[2] + sm.sws[3] + wself;
            float hv = fmaxf(sm.ht[lane] + agg + att / wsum + bgl[lane], 0.f);
            if (LM == 2) heads_eval(hv, lane, p);
            else hout[(size_t)t * HD + lane] = hv;
        }
        __syncthreads();
    }
}

// ---------- layer 0 kernel (identical structure to r7's k_layer<0>) ----------
__global__ __launch_bounds__(256) void k_layer0(KP p) {
    __shared__ SMem sm;
    layer_phase<0>(p, sm, (const float*)nullptr, p.hB);
}

// ---------- merged layers 1+2: 32 blocks, cheap spin barrier, block 0 finishes ----------
__global__ __launch_bounds__(256) void k_layer12(KP p) {
    __shared__ SMem sm;
    layer_phase<1>(p, sm, p.hB, p.hA);

    // barrier among L12BLK blocks (arrive; exit unless block 0; block 0 spins)
    __builtin_amdgcn_fence(__ATOMIC_RELEASE, "agent");
    __syncthreads();
    if (threadIdx.x == 0) atomicAdd(&p.cnt[2], 1);
    if (blockIdx.x != 0) return;
    if (threadIdx.x == 0) {
        while (__hip_atomic_load(&p.cnt[2], __ATOMIC_RELAXED, __HIP_MEMORY_SCOPE_AGENT) < L12BLK)
            __builtin_amdgcn_s_sleep(8);
    }
    __syncthreads();
    __builtin_amdgcn_fence(__ATOMIC_ACQUIRE, "agent");

    layer_phase<2>(p, sm, p.hA, p.out);
}

extern "C" void kernel_launch(void* const* d_in, const int* in_sizes, int n_in,
                              void* d_out, int out_size, void* d_ws, size_t ws_size,
                              hipStream_t stream) {
    KP p;
    p.x      = (const float*)d_in[0];
    p.ei     = (const int*)d_in[1];
    // d_in[2] edge_attr and d_in[7..10] (edge encoder) are dead code in the reference
    p.Wn     = (const float*)d_in[3];
    p.bn     = (const float*)d_in[4];
    p.gn     = (const float*)d_in[5];
    p.betan  = (const float*)d_in[6];
    p.Wc1    = (const float*)d_in[11];
    p.bc1    = (const float*)d_in[12];
    p.Wc2    = (const float*)d_in[13];
    p.bc2    = (const float*)d_in[14];
    p.Wg     = (const float*)d_in[15];
    p.att_s  = (const float*)d_in[16];
    p.att_d  = (const float*)d_in[17];
    p.bg     = (const float*)d_in[18];
    p.Wq1    = (const float*)d_in[19];
    p.bq1    = (const float*)d_in[20];
    p.gq     = (const float*)d_in[21];
    p.betaq  = (const float*)d_in[22];
    p.Wq2    = (const float*)d_in[23];
    p.bq2    = (const float*)d_in[24];
    p.Wv1    = (const float*)d_in[25];
    p.bv1    = (const float*)d_in[26];
    p.gv     = (const float*)d_in[27];
    p.betav  = (const float*)d_in[28];
    p.Wv2    = (const float*)d_in[29];
    p.bv2    = (const float*)d_in[30];
    p.out    = (float*)d_out;

    // ---- workspace layout (identical ordering to r7/r8)
    p.hB    = (float*)d_ws;                         // N*HD
    p.hA    = p.hB + (size_t)N_NODES * HD;          // N*HD
    p.need1 = (int*)(p.hA + (size_t)N_NODES * HD);  // zero-zone start (16B aligned)
    p.need2 = p.need1 + N_NODES;
    p.deg1  = p.need2 + N_NODES;                    // T_CAP
    p.deg2  = p.deg1 + T_CAP;                       // T2_CAP
    p.deg3  = p.deg2 + T2_CAP;                      // 4
    p.cnt   = p.deg3 + 4;                           // 8: cnt0,cnt1,done12 (zero-zone end)
    p.idx1  = p.cnt + 8;                            // N
    p.idx2  = p.idx1 + N_NODES;                     // N
    p.list1 = p.idx2 + N_NODES;                     // T_CAP
    p.list2 = p.list1 + T_CAP;                      // T2_CAP
    p.eb1   = p.list2 + T2_CAP;                     // T_CAP*MAXDEG
    p.eb2   = p.eb1 + (size_t)T_CAP * MAXDEG;       // T2_CAP*MAXDEG
    p.eb3   = p.eb2 + (size_t)T2_CAP * MAXDEG;      // MAXDEG

    const int zero_ints = 2 * N_NODES + T_CAP + T2_CAP + 12;   // 108716, /4 exact
    const int n4 = zero_ints / 4;                   // 27179 int4
    const int EB = (N_EDGES + 255) / 256;           // 3125 blocks

    k_zero<<<(n4 + 255) / 256, 256, 0, stream>>>((int4*)p.need1, n4);
    k_scanA<<<EB, 256, 0, stream>>>(p.ei, p.need1, p.need2, p.list1, p.list2,
                                    p.idx1, p.idx2, p.cnt, p.eb3, p.deg3);
    k_scanB<<<EB, 256, 0, stream>>>(p.ei, p.need2, p.idx2,
                                    p.need1, p.list1, p.idx1, p.cnt, p.eb2, p.deg2);
    k_scanC<<<EB, 256, 0, stream>>>(p.ei, p.need1, p.idx1, p.eb1, p.deg1);
    k_layer0<<<512, 256, 0, stream>>>(p);
    k_layer12<<<L12BLK, 256, 0, stream>>>(p);
}